// Round 7
// baseline (1504.188 us; speedup 1.0000x reference)
//
#include <hip/hip_runtime.h>

#define NN   50000
#define NE   400000
#define NET  450000   // NE + NN self loops
#define NG   64
#define NEG  0.2f

__device__ inline float b2f(unsigned short u){
  union{unsigned int i; float f;} v; v.i = ((unsigned int)u) << 16; return v.f;
}
__device__ inline unsigned short f2b(float f){
  union{float f; unsigned int i;} v; v.f = f;
  unsigned int r = (v.i + 0x7fffu + ((v.i >> 16) & 1u)) >> 16;
  return (unsigned short)r;
}
__device__ inline float sane(float o){
  return (o > -1e30f && o < 1e30f) ? o : 0.f;   // NaN/inf -> 0 (safety net only)
}
// monotone float <-> uint for atomicMax on signed floats
__device__ inline unsigned int encf(float f){
  unsigned int u = __float_as_uint(f);
  return (u & 0x80000000u) ? ~u : (u | 0x80000000u);
}
__device__ inline float decf(unsigned int u){
  return __uint_as_float((u & 0x80000000u) ? (u ^ 0x80000000u) : ~u);
}

// ---------------- input dtype detection + canonicalization ----------------
// f32 N(0,1) data read as u16: even halves are mantissa bits, ~uniform -> many
// "exponent" fields >= 0xD0. bf16 N(0,1) never exceeds ~0x41. Proven on HW (r5).
__global__ void detect_dtype(const unsigned short* __restrict__ x, int* __restrict__ flag){
  int tid = threadIdx.x;
  int hit = 0;
  for (int i = tid; i < 4096; i += 256){
    int ex = (x[i] >> 7) & 0xFF;
    if (ex >= 0xD0) hit = 1;
  }
  unsigned long long b = __ballot(hit != 0);
  __shared__ int s[4];
  if ((tid & 63) == 0) s[tid >> 6] = (b != 0ull) ? 1 : 0;
  __syncthreads();
  if (tid == 0) flag[0] = (s[0] | s[1] | s[2] | s[3]);   // 1 => input buffers are f32
}

__global__ void cvt_bf16(const void* __restrict__ src, unsigned short* __restrict__ dst,
                         int n, const int* __restrict__ flag){
  int i = blockIdx.x * 256 + threadIdx.x;
  if (i >= n) return;
  if (flag[0]) dst[i] = f2b(((const float*)src)[i]);
  else         dst[i] = ((const unsigned short*)src)[i];
}

__global__ void cvt_f32(const void* __restrict__ src, float* __restrict__ dst,
                        int n, const int* __restrict__ flag){
  int i = blockIdx.x * 256 + threadIdx.x;
  if (i >= n) return;
  if (flag[0]) dst[i] = ((const float*)src)[i];
  else         dst[i] = b2f(((const unsigned short*)src)[i]);
}

// ---------------- GEMM layer 1: buf[M x 256] bf16 = xb[M x 128] bf16 @ W[128 x 256] f32 ----------------
__global__ void gemm1_valu(const unsigned short* __restrict__ A,
                           const float* __restrict__ W,
                           unsigned short* __restrict__ C, int M){
  __shared__ float As[4][128];
  int tid = threadIdx.x;
  int row0 = blockIdx.x * 4;
  for (int idx = tid; idx < 4 * 128; idx += 256){
    int r = idx >> 7, k = idx & 127;
    int rr = row0 + r;
    As[r][k] = (rr < M) ? b2f(A[(size_t)rr * 128 + k]) : 0.f;
  }
  __syncthreads();
  int c = tid;
  float a0 = 0.f, a1 = 0.f, a2 = 0.f, a3 = 0.f;
#pragma unroll 4
  for (int k = 0; k < 128; k++){
    float w = W[k * 256 + c];
    a0 += As[0][k] * w;
    a1 += As[1][k] * w;
    a2 += As[2][k] * w;
    a3 += As[3][k] * w;
  }
  if (row0 + 0 < M) C[(size_t)(row0 + 0) * 256 + c] = f2b(a0);
  if (row0 + 1 < M) C[(size_t)(row0 + 1) * 256 + c] = f2b(a1);
  if (row0 + 2 < M) C[(size_t)(row0 + 2) * 256 + c] = f2b(a2);
  if (row0 + 3 < M) C[(size_t)(row0 + 3) * 256 + c] = f2b(a3);
}

// ---------------- GEMM layer 2 IN-PLACE: buf rows hold h1[256] bf16; write xw2 into cols 0..127 ----------------
__global__ void gemm2_valu(unsigned short* __restrict__ buf,
                           const float* __restrict__ W, int M){
  __shared__ float As[8][256];
  int tid = threadIdx.x;
  int row0 = blockIdx.x * 8;
  for (int idx = tid; idx < 8 * 256; idx += 256){
    int r = idx >> 8, k = idx & 255;
    int rr = row0 + r;
    As[r][k] = (rr < M) ? b2f(buf[(size_t)rr * 256 + k]) : 0.f;
  }
  __syncthreads();
  int c = tid & 127;
  int rg = (tid >> 7) * 4;          // 0 or 4
  float a0 = 0.f, a1 = 0.f, a2 = 0.f, a3 = 0.f;
#pragma unroll 4
  for (int k = 0; k < 256; k++){
    float w = W[k * 128 + c];
    a0 += As[rg + 0][k] * w;
    a1 += As[rg + 1][k] * w;
    a2 += As[rg + 2][k] * w;
    a3 += As[rg + 3][k] * w;
  }
  if (row0 + rg + 0 < M) buf[(size_t)(row0 + rg + 0) * 256 + c] = f2b(a0);
  if (row0 + rg + 1 < M) buf[(size_t)(row0 + rg + 1) * 256 + c] = f2b(a1);
  if (row0 + rg + 2 < M) buf[(size_t)(row0 + rg + 2) * 256 + c] = f2b(a2);
  if (row0 + rg + 3 < M) buf[(size_t)(row0 + rg + 3) * 256 + c] = f2b(a3);
}

// ---------------- attention coefficients: one thread per (node,head) ----------------
__global__ void attn1_simple(const unsigned short* __restrict__ xw,
                             const float* __restrict__ asrc,
                             const float* __restrict__ adst,
                             float* __restrict__ a_s, float* __restrict__ a_d){
  int t = blockIdx.x * 256 + threadIdx.x;
  if (t >= NN * 4) return;
  int n = t >> 2, h = t & 3;
  float s = 0.f, d = 0.f;
  for (int c = 0; c < 64; c++){
    float x = b2f(xw[(size_t)n * 256 + h * 64 + c]);
    s += x * asrc[h * 64 + c];
    d += x * adst[h * 64 + c];
  }
  a_s[t] = s; a_d[t] = d;    // layout [n*4+h]
}

__global__ void attn2_simple(const unsigned short* __restrict__ xw2,  // stride 256, cols 0..127
                             const float* __restrict__ asrc,
                             const float* __restrict__ adst,
                             float* __restrict__ a_s, float* __restrict__ a_d){
  int n = blockIdx.x * 256 + threadIdx.x;
  if (n >= NN) return;
  float s = 0.f, d = 0.f;
  for (int c = 0; c < 128; c++){
    float x = b2f(xw2[(size_t)n * 256 + c]);
    s += x * asrc[c];
    d += x * adst[c];
  }
  a_s[n] = s; a_d[n] = d;
}

// ---------------- layer 1 softmax: literal segment_max / segment_sum via atomics ----------------
__global__ void epass1(const int* __restrict__ ei, const float* __restrict__ a_s,
                       const float* __restrict__ a_d, unsigned short* __restrict__ e1,
                       unsigned int* __restrict__ m1){
  int t = blockIdx.x * 256 + threadIdx.x;
  if (t >= NET) return;
  int s = (t < NE) ? ei[t]      : (t - NE);
  int d = (t < NE) ? ei[NE + t] : (t - NE);
#pragma unroll
  for (int h = 0; h < 4; h++){
    float e = a_s[s * 4 + h] + a_d[d * 4 + h];
    e = e > 0.f ? e : NEG * e;
    unsigned short eb = f2b(e);
    e1[(size_t)t * 4 + h] = eb;
    atomicMax(&m1[d * 4 + h], encf(b2f(eb)));
  }
}

__global__ void denpass1(const int* __restrict__ ei, unsigned short* __restrict__ e1,
                         const unsigned int* __restrict__ m1, float* __restrict__ den1){
  int t = blockIdx.x * 256 + threadIdx.x;
  if (t >= NET) return;
  int d = (t < NE) ? ei[NE + t] : (t - NE);
#pragma unroll
  for (int h = 0; h < 4; h++){
    float e = b2f(e1[(size_t)t * 4 + h]);
    float m = decf(m1[d * 4 + h]);
    float ee = __expf(e - m);
    unsigned short eb = f2b(ee);
    e1[(size_t)t * 4 + h] = eb;               // now holds exp(e-m), bf16
    atomicAdd(&den1[d * 4 + h], b2f(eb));     // den consistent with stored value
  }
}

// message scatter, 64-channel chunk: thread = (edge, channel-in-chunk)
__global__ void msgpass1(const int* __restrict__ ei, const unsigned short* __restrict__ e1,
                         const float* __restrict__ den1, const unsigned short* __restrict__ xw1,
                         float* __restrict__ acc, int c0){
  int idx = blockIdx.x * 256 + threadIdx.x;
  if (idx >= NET * 64) return;
  int t = idx >> 6;
  int c = (idx & 63) + c0;
  int s = (t < NE) ? ei[t]      : (t - NE);
  int d = (t < NE) ? ei[NE + t] : (t - NE);
  int h = c >> 6;
  float alpha = b2f(e1[(size_t)t * 4 + h]) / den1[d * 4 + h];
  atomicAdd(&acc[(size_t)d * 64 + (c & 63)], alpha * b2f(xw1[(size_t)s * 256 + c]));
}

// finish chunk: add bias, ELU, write h1 back into buf (chunk fully consumed), re-zero acc
__global__ void convert1(float* __restrict__ acc, const float* __restrict__ bias,
                         unsigned short* __restrict__ buf, int c0){
  int idx = blockIdx.x * 256 + threadIdx.x;   // NN*64
  int n = idx >> 6, cc = idx & 63;
  float v = acc[idx];
  acc[idx] = 0.f;
  v += bias[c0 + cc];
  v = v > 0.f ? v : expm1f(v);
  buf[(size_t)n * 256 + c0 + cc] = f2b(sane(v));
}

// ---------------- layer 2 softmax (1 head) ----------------
__global__ void epass2(const int* __restrict__ ei, const float* __restrict__ a_s,
                       const float* __restrict__ a_d, unsigned short* __restrict__ e2,
                       unsigned int* __restrict__ m2){
  int t = blockIdx.x * 256 + threadIdx.x;
  if (t >= NET) return;
  int s = (t < NE) ? ei[t]      : (t - NE);
  int d = (t < NE) ? ei[NE + t] : (t - NE);
  float e = a_s[s] + a_d[d];
  e = e > 0.f ? e : NEG * e;
  unsigned short eb = f2b(e);
  e2[t] = eb;
  atomicMax(&m2[d], encf(b2f(eb)));
}

__global__ void denpass2(const int* __restrict__ ei, unsigned short* __restrict__ e2,
                         const unsigned int* __restrict__ m2, float* __restrict__ den2){
  int t = blockIdx.x * 256 + threadIdx.x;
  if (t >= NET) return;
  int d = (t < NE) ? ei[NE + t] : (t - NE);
  float e = b2f(e2[t]);
  float ee = __expf(e - decf(m2[d]));
  unsigned short eb = f2b(ee);
  e2[t] = eb;
  atomicAdd(&den2[d], b2f(eb));
}

__global__ void msgpass2(const int* __restrict__ ei, const unsigned short* __restrict__ e2,
                         const float* __restrict__ den2, const unsigned short* __restrict__ xw2,
                         float* __restrict__ acc, int c0){
  int idx = blockIdx.x * 256 + threadIdx.x;
  if (idx >= NET * 64) return;
  int t = idx >> 6;
  int c = (idx & 63) + c0;
  int s = (t < NE) ? ei[t]      : (t - NE);
  int d = (t < NE) ? ei[NE + t] : (t - NE);
  float alpha = b2f(e2[t]) / den2[d];
  atomicAdd(&acc[(size_t)d * 64 + (c & 63)], alpha * b2f(xw2[(size_t)s * 256 + c]));
}

// write h as FLOAT32 into d_out (reference output dtype is float32)
__global__ void convert2(float* __restrict__ acc, const float* __restrict__ bias,
                         float* __restrict__ hout, int c0){
  int idx = blockIdx.x * 256 + threadIdx.x;   // NN*64
  int n = idx >> 6, cc = idx & 63;
  float v = acc[idx];
  acc[idx] = 0.f;
  v += bias[c0 + cc];
  v = v > 0.f ? v : expm1f(v);
  hout[(size_t)n * 128 + c0 + cc] = sane(v);
}

// ---------------- pooling: literal per-node atomics (reads f32 h from d_out) ----------------
__global__ void pool_simple(const float* __restrict__ h, const int* __restrict__ batch,
                            float* __restrict__ pools, int* __restrict__ cnt){
  int n = blockIdx.x;
  int c = threadIdx.x;      // 128
  if (n >= NN) return;
  int g = batch[n];
  g = (g < 0) ? 0 : (g >= NG ? NG - 1 : g);
  atomicAdd(&pools[g * 128 + c], h[(size_t)n * 128 + c]);
  if (c == 0) atomicAdd(&cnt[g], 1);
}

__global__ void final_kernel(const float* __restrict__ pools, const int* __restrict__ cnt,
                             float* __restrict__ out){
  int g = blockIdx.x, c = threadIdx.x;
  float d = fmaxf((float)cnt[g], 1.0f);
  out[g * 128 + c] = sane(pools[g * 128 + c] / d);
}

extern "C" void kernel_launch(void* const* d_in, const int* in_sizes, int n_in,
                              void* d_out, int out_size, void* d_ws, size_t ws_size,
                              hipStream_t stream){
  const void* x_raw   = d_in[0];
  const int*  ei      = (const int*)d_in[1];
  const int*  bat     = (const int*)d_in[2];

  // workspace: ~60.5 MB, control structures first, big feature buffers last
  char* w = (char*)d_ws;
  size_t o = 0;
  auto carve = [&](size_t bytes) -> char* {
    char* p = w + o; o += (bytes + 255) & ~(size_t)255; return p;
  };
  int*            flag  = (int*)carve(256);
  float*          wf1   = (float*)carve((size_t)128 * 256 * 4);
  float*          wf2   = (float*)carve((size_t)256 * 128 * 4);
  float*          av1   = (float*)carve(256 * 4);
  float*          dv1   = (float*)carve(256 * 4);
  float*          b1f   = (float*)carve(256 * 4);
  float*          av2   = (float*)carve(128 * 4);
  float*          dv2   = (float*)carve(128 * 4);
  float*          b2f_  = (float*)carve(128 * 4);
  float*          a_s1v = (float*)carve((size_t)NN * 4 * 4);
  float*          a_d1v = (float*)carve((size_t)NN * 4 * 4);
  unsigned int*   m1    = (unsigned int*)carve((size_t)NN * 4 * 4);
  float*          den1  = (float*)carve((size_t)NN * 4 * 4);
  float*          a_s2v = (float*)carve((size_t)NN * 4);
  float*          a_d2v = (float*)carve((size_t)NN * 4);
  unsigned int*   m2    = (unsigned int*)carve((size_t)NN * 4);
  float*          den2  = (float*)carve((size_t)NN * 4);
  float*          pools = (float*)carve((size_t)NG * 128 * 4);
  int*            cnt   = (int*)carve((size_t)NG * 4);
  unsigned short* e1    = (unsigned short*)carve((size_t)NET * 4 * 2);  // 3.6 MB
  unsigned short* e2    = (unsigned short*)carve((size_t)NET * 2);      // 0.9 MB
  float*          acc   = (float*)carve((size_t)NN * 64 * 4);           // 12.8 MB
  unsigned short* xb    = (unsigned short*)carve((size_t)NN * 128 * 2); // 12.8 MB
  unsigned short* buf   = (unsigned short*)carve((size_t)NN * 256 * 2); // 25.6 MB

  float* out_ge = (float*)d_out;                 // output dtype: FLOAT32
  float* out_h  = (float*)d_out + NG * 128;

  hipMemsetAsync(m1,    0, (size_t)NN * 4 * 4,   stream);
  hipMemsetAsync(den1,  0, (size_t)NN * 4 * 4,   stream);
  hipMemsetAsync(m2,    0, (size_t)NN * 4,       stream);
  hipMemsetAsync(den2,  0, (size_t)NN * 4,       stream);
  hipMemsetAsync(acc,   0, (size_t)NN * 64 * 4,  stream);
  hipMemsetAsync(pools, 0, (size_t)NG * 128 * 4, stream);
  hipMemsetAsync(cnt,   0, (size_t)NG * 4,       stream);

  // ---- dtype detection + canonicalization (inputs proven f32 on HW, r5) ----
  detect_dtype<<<1, 256, 0, stream>>>((const unsigned short*)x_raw, flag);
  cvt_bf16<<<(NN * 128 + 255) / 256, 256, 0, stream>>>(x_raw, xb, NN * 128, flag);
  cvt_f32<<<128, 256, 0, stream>>>(d_in[3], wf1, 128 * 256, flag);
  cvt_f32<<<1, 256, 0, stream>>>(d_in[4], av1, 256, flag);
  cvt_f32<<<1, 256, 0, stream>>>(d_in[5], dv1, 256, flag);
  cvt_f32<<<1, 256, 0, stream>>>(d_in[6], b1f, 256, flag);
  cvt_f32<<<128, 256, 0, stream>>>(d_in[7], wf2, 256 * 128, flag);
  cvt_f32<<<1, 256, 0, stream>>>(d_in[8], av2, 128, flag);
  cvt_f32<<<1, 256, 0, stream>>>(d_in[9], dv2, 128, flag);
  cvt_f32<<<1, 256, 0, stream>>>(d_in[10], b2f_, 128, flag);

  // ---- layer 1 ----
  gemm1_valu<<<12500, 256, 0, stream>>>(xb, wf1, buf, NN);
  attn1_simple<<<(NN * 4 + 255) / 256, 256, 0, stream>>>(buf, av1, dv1, a_s1v, a_d1v);
  epass1<<<(NET + 255) / 256, 256, 0, stream>>>(ei, a_s1v, a_d1v, e1, m1);
  denpass1<<<(NET + 255) / 256, 256, 0, stream>>>(ei, e1, m1, den1);
  for (int c0 = 0; c0 < 256; c0 += 64){
    msgpass1<<<NET * 64 / 256, 256, 0, stream>>>(ei, e1, den1, buf, acc, c0);
    convert1<<<NN * 64 / 256, 256, 0, stream>>>(acc, b1f, buf, c0);
  }

  // ---- layer 2 ----
  gemm2_valu<<<6250, 256, 0, stream>>>(buf, wf2, NN);
  attn2_simple<<<(NN + 255) / 256, 256, 0, stream>>>(buf, av2, dv2, a_s2v, a_d2v);
  epass2<<<(NET + 255) / 256, 256, 0, stream>>>(ei, a_s2v, a_d2v, e2, m2);
  denpass2<<<(NET + 255) / 256, 256, 0, stream>>>(ei, e2, m2, den2);
  for (int c0 = 0; c0 < 128; c0 += 64){
    msgpass2<<<NET * 64 / 256, 256, 0, stream>>>(ei, e2, den2, buf, acc, c0);
    convert2<<<NN * 64 / 256, 256, 0, stream>>>(acc, b2f_, out_h, c0);
  }

  // ---- pooling ----
  pool_simple<<<NN, 128, 0, stream>>>(out_h, bat, pools, cnt);
  final_kernel<<<NG, 128, 0, stream>>>(pools, cnt, out_ge);
}

// Round 8
// 392.251 us; speedup vs baseline: 3.8348x; 3.8348x over previous
//
#include <hip/hip_runtime.h>

#define NN   50000
#define NE   400000
#define NET  450000   // NE + NN self loops
#define NG   64
#define NEG  0.2f

using bf16x8 = __attribute__((ext_vector_type(8))) short;
using f32x4  = __attribute__((ext_vector_type(4))) float;

__device__ inline float b2f(unsigned short u){
  union{unsigned int i; float f;} v; v.i = ((unsigned int)u) << 16; return v.f;
}
__device__ inline unsigned short f2b(float f){
  union{float f; unsigned int i;} v; v.f = f;
  unsigned int r = (v.i + 0x7fffu + ((v.i >> 16) & 1u)) >> 16;
  return (unsigned short)r;
}
__device__ inline float sane(float o){
  return (o > -1e30f && o < 1e30f) ? o : 0.f;
}

// ---------------- input dtype detection + canonicalization (HW-proven r5/r7) ----------------
__global__ void detect_dtype(const unsigned short* __restrict__ x, int* __restrict__ flag){
  int tid = threadIdx.x;
  int hit = 0;
  for (int i = tid; i < 4096; i += 256){
    int ex = (x[i] >> 7) & 0xFF;
    if (ex >= 0xD0) hit = 1;
  }
  unsigned long long b = __ballot(hit != 0);
  __shared__ int s[4];
  if ((tid & 63) == 0) s[tid >> 6] = (b != 0ull) ? 1 : 0;
  __syncthreads();
  if (tid == 0) flag[0] = (s[0] | s[1] | s[2] | s[3]);   // 1 => inputs are f32
}

__global__ void cvt_bf16(const void* __restrict__ src, unsigned short* __restrict__ dst,
                         int n, const int* __restrict__ flag){
  int i = blockIdx.x * 256 + threadIdx.x;
  if (i >= n) return;
  if (flag[0]) dst[i] = f2b(((const float*)src)[i]);
  else         dst[i] = ((const unsigned short*)src)[i];
}

__global__ void cvt_f32(const void* __restrict__ src, float* __restrict__ dst,
                        int n, const int* __restrict__ flag){
  int i = blockIdx.x * 256 + threadIdx.x;
  if (i >= n) return;
  if (flag[0]) dst[i] = ((const float*)src)[i];
  else         dst[i] = b2f(((const unsigned short*)src)[i]);
}

// ---------------- pack W [K x N] bf16 -> MFMA B-fragment order ----------------
// Bp[((nt*NK + kit)*64 + lane)*8 + j] = W[(kit*32 + (lane>>4)*8 + j)*N + nt*16 + (lane&15)]
__global__ void pack_w(const unsigned short* __restrict__ W, unsigned short* __restrict__ Bp,
                       int K, int N){
  int t = blockIdx.x * blockDim.x + threadIdx.x;
  int nk = K / 32;
  int total = (N / 16) * nk * 64;
  if (t >= total) return;
  int lane = t & 63; int rest = t >> 6;
  int kit = rest % nk; int nt = rest / nk;
  int quad = lane >> 4, n = lane & 15;
  unsigned short* dst = Bp + (size_t)t * 8;
#pragma unroll
  for (int j = 0; j < 8; j++)
    dst[j] = W[(size_t)(kit*32 + quad*8 + j) * N + nt*16 + n];
}

// ---------------- MFMA GEMM: C[M x Nc] bf16 = A[M x K] bf16 @ Bp(packed) ----------------
// Layouts match HW-verified m91-m97 ladder: A[m=lane&15][k=quad*8+j], C col=lane&15,row=quad*4+r
template<int K, int NT>
__global__ void gemm_mfma(const unsigned short* __restrict__ A,
                          const unsigned short* __restrict__ Bp,
                          unsigned short* __restrict__ C, int M, int Nc){
  constexpr int NK = K / 32;
  int lane = threadIdx.x & 63, wave = threadIdx.x >> 6;
  int mbase = (blockIdx.x * 4 + wave) * 16;
  if (mbase >= M) return;
  int quad = lane >> 4, nn = lane & 15;
  int arow = mbase + nn; if (arow >= M) arow = M - 1;
  const unsigned short* Arow = A + (size_t)arow * K + quad * 8;
  bf16x8 afrag[NK];
#pragma unroll
  for (int kit = 0; kit < NK; kit++)
    afrag[kit] = *(const bf16x8*)(Arow + kit * 32);
  for (int nt = 0; nt < NT; nt++){
    f32x4 acc = {0.f, 0.f, 0.f, 0.f};
#pragma unroll
    for (int kit = 0; kit < NK; kit++){
      bf16x8 bfrag = *(const bf16x8*)(Bp + ((size_t)(nt*NK + kit) * 64 + lane) * 8);
      acc = __builtin_amdgcn_mfma_f32_16x16x32_bf16(afrag[kit], bfrag, acc, 0, 0, 0);
    }
#pragma unroll
    for (int r = 0; r < 4; r++){
      int row = mbase + quad * 4 + r;
      if (row < M) C[(size_t)row * Nc + nt*16 + nn] = f2b(acc[r]);
    }
  }
}

// ---------------- attn coeffs layer 1: wave per node, lane owns 4 channels (head = lane>>4) ----------------
__global__ void attn1_fast(const unsigned short* __restrict__ xw, const float* __restrict__ av,
                           const float* __restrict__ dv, float* __restrict__ a_s,
                           float* __restrict__ a_d){
  int lane = threadIdx.x & 63;
  int n = (blockIdx.x * blockDim.x + threadIdx.x) >> 6;
  if (n >= NN) return;
  ushort4 xv = *(const ushort4*)(xw + (size_t)n * 256 + lane * 4);
  float4 a4 = *(const float4*)(av + lane * 4);
  float4 d4 = *(const float4*)(dv + lane * 4);
  float x0 = b2f(xv.x), x1 = b2f(xv.y), x2 = b2f(xv.z), x3 = b2f(xv.w);
  float s = x0*a4.x + x1*a4.y + x2*a4.z + x3*a4.w;
  float d = x0*d4.x + x1*d4.y + x2*d4.z + x3*d4.w;
#pragma unroll
  for (int off = 8; off; off >>= 1){ s += __shfl_xor(s, off); d += __shfl_xor(d, off); }
  if ((lane & 15) == 0){
    int h = lane >> 4;
    a_s[n * 4 + h] = s; a_d[n * 4 + h] = d;
  }
}

// ---------------- attn coeffs layer 2: wave per node, lane owns 2 channels ----------------
__global__ void attn2_fast(const unsigned short* __restrict__ xw, const float* __restrict__ av,
                           const float* __restrict__ dv, float* __restrict__ a_s,
                           float* __restrict__ a_d){
  int lane = threadIdx.x & 63;
  int n = (blockIdx.x * blockDim.x + threadIdx.x) >> 6;
  if (n >= NN) return;
  ushort2 xv = *(const ushort2*)(xw + (size_t)n * 128 + lane * 2);
  float x0 = b2f(xv.x), x1 = b2f(xv.y);
  float s = x0 * av[lane*2] + x1 * av[lane*2+1];
  float d = x0 * dv[lane*2] + x1 * dv[lane*2+1];
#pragma unroll
  for (int off = 32; off; off >>= 1){ s += __shfl_xor(s, off); d += __shfl_xor(d, off); }
  if (lane == 0){ a_s[n] = s; a_d[n] = d; }
}

// ---------------- CSR build ----------------
__global__ void count_deg(const int* __restrict__ ei, int* __restrict__ deg){
  int t = blockIdx.x * blockDim.x + threadIdx.x;
  if (t >= NET) return;
  int d = (t < NE) ? ei[NE + t] : (t - NE);
  if (d < 0) d = 0; if (d >= NN) d = NN - 1;
  atomicAdd(&deg[d], 1);
}

__global__ void scan_block(const int* __restrict__ in, int* __restrict__ out_excl,
                           int* __restrict__ bsums, int n){
  __shared__ int s[256];
  int tid = threadIdx.x, gid = blockIdx.x * 256 + tid;
  int v = (gid < n) ? in[gid] : 0;
  s[tid] = v; __syncthreads();
  for (int off = 1; off < 256; off <<= 1){
    int t = (tid >= off) ? s[tid - off] : 0;
    __syncthreads();
    s[tid] += t;
    __syncthreads();
  }
  if (gid < n) out_excl[gid] = s[tid] - v;
  if (tid == 255) bsums[blockIdx.x] = s[255];
}

__global__ void scan_sums(int* __restrict__ bs, int nb){
  __shared__ int s[256];
  int tid = threadIdx.x;
  int v = (tid < nb) ? bs[tid] : 0;
  s[tid] = v; __syncthreads();
  for (int off = 1; off < 256; off <<= 1){
    int t = (tid >= off) ? s[tid - off] : 0;
    __syncthreads();
    s[tid] += t;
    __syncthreads();
  }
  if (tid < nb) bs[tid] = s[tid] - v;
}

__global__ void scan_add(int* __restrict__ offs, const int* __restrict__ bs,
                         int* __restrict__ cursor, int n){
  int gid = blockIdx.x * 256 + threadIdx.x;
  if (gid < n){
    int o = offs[gid] + bs[blockIdx.x];
    offs[gid] = o; cursor[gid] = o;
  }
  if (gid == 0) offs[n] = NET;
}

__global__ void fill_csr(const int* __restrict__ ei, int* __restrict__ cursor,
                         int* __restrict__ csr){
  int t = blockIdx.x * blockDim.x + threadIdx.x;
  if (t >= NET) return;
  int s = (t < NE) ? ei[t]      : (t - NE);
  int d = (t < NE) ? ei[NE + t] : (t - NE);
  if (d < 0) d = 0; if (d >= NN) d = NN - 1;
  int pos = atomicAdd(&cursor[d], 1);
  if (pos >= 0 && pos < NET) csr[pos] = s;
}

// ---------------- layer-1 aggregation: wave per dst node, online softmax, zero feature atomics ----------------
__global__ void agg1(const unsigned short* __restrict__ xw, const float* __restrict__ a_s,
                     const float* __restrict__ a_d, const int* __restrict__ offs,
                     const int* __restrict__ csr, const float* __restrict__ bias,
                     unsigned short* __restrict__ h1){
  int lane = threadIdx.x & 63;
  int node = (blockIdx.x * blockDim.x + threadIdx.x) >> 6;
  if (node >= NN) return;
  int h = lane >> 4;                      // head owning channels 4*lane..4*lane+3
  int beg = offs[node], end = offs[node + 1];
  if (beg < 0) beg = 0; if (end > NET) end = NET;
  float4 advv = *(const float4*)(a_d + (size_t)node * 4);
  float adv = (h == 0) ? advv.x : (h == 1) ? advv.y : (h == 2) ? advv.z : advv.w;
  float m = -1e30f, l = 0.f, c0 = 0.f, c1 = 0.f, c2 = 0.f, c3 = 0.f;
  for (int e = beg; e < end; e++){
    int src = csr[e];
    src = (src < 0) ? 0 : (src >= NN ? NN - 1 : src);
    float4 asvv = *(const float4*)(a_s + (size_t)src * 4);
    float as = (h == 0) ? asvv.x : (h == 1) ? asvv.y : (h == 2) ? asvv.z : asvv.w;
    float ev = as + adv; ev = ev > 0.f ? ev : NEG * ev;
    float mn = fmaxf(m, ev);
    float sc = __expf(m - mn), p = __expf(ev - mn);
    ushort4 xv = *(const ushort4*)(xw + (size_t)src * 256 + lane * 4);
    l  = l  * sc + p;
    c0 = c0 * sc + p * b2f(xv.x);
    c1 = c1 * sc + p * b2f(xv.y);
    c2 = c2 * sc + p * b2f(xv.z);
    c3 = c3 * sc + p * b2f(xv.w);
    m = mn;
  }
  if (!(l > 0.f)) l = 1.f;
  float inv = 1.f / l;
  float4 b4 = *(const float4*)(bias + lane * 4);
  float v; ushort4 o;
  v = c0 * inv + b4.x; v = v > 0.f ? v : expm1f(v); o.x = f2b(sane(v));
  v = c1 * inv + b4.y; v = v > 0.f ? v : expm1f(v); o.y = f2b(sane(v));
  v = c2 * inv + b4.z; v = v > 0.f ? v : expm1f(v); o.z = f2b(sane(v));
  v = c3 * inv + b4.w; v = v > 0.f ? v : expm1f(v); o.w = f2b(sane(v));
  *(ushort4*)(h1 + (size_t)node * 256 + lane * 4) = o;
}

// ---------------- layer-2 aggregation: wave per dst node; writes f32 h into d_out ----------------
__global__ void agg2(const unsigned short* __restrict__ xw, const float* __restrict__ a_s,
                     const float* __restrict__ a_d, const int* __restrict__ offs,
                     const int* __restrict__ csr, const float* __restrict__ bias,
                     float* __restrict__ hout){
  int lane = threadIdx.x & 63;
  int node = (blockIdx.x * blockDim.x + threadIdx.x) >> 6;
  if (node >= NN) return;
  int beg = offs[node], end = offs[node + 1];
  if (beg < 0) beg = 0; if (end > NET) end = NET;
  float adv = a_d[node];
  float m = -1e30f, l = 0.f, c0 = 0.f, c1 = 0.f;
  for (int e = beg; e < end; e++){
    int src = csr[e];
    src = (src < 0) ? 0 : (src >= NN ? NN - 1 : src);
    float ev = a_s[src] + adv; ev = ev > 0.f ? ev : NEG * ev;
    float mn = fmaxf(m, ev);
    float sc = __expf(m - mn), p = __expf(ev - mn);
    ushort2 xv = *(const ushort2*)(xw + (size_t)src * 128 + lane * 2);
    l  = l  * sc + p;
    c0 = c0 * sc + p * b2f(xv.x);
    c1 = c1 * sc + p * b2f(xv.y);
    m = mn;
  }
  if (!(l > 0.f)) l = 1.f;
  float inv = 1.f / l;
  float v0 = c0 * inv + bias[lane*2];   v0 = v0 > 0.f ? v0 : expm1f(v0);
  float v1 = c1 * inv + bias[lane*2+1]; v1 = v1 > 0.f ? v1 : expm1f(v1);
  float2 o; o.x = sane(v0); o.y = sane(v1);
  *(float2*)(hout + (size_t)node * 128 + lane * 2) = o;
}

// ---------------- mean pooling: sorted batch, per-block run accumulation ----------------
__global__ void pool_kernel(const float* __restrict__ h, const int* __restrict__ batch,
                            float* __restrict__ pools, int* __restrict__ cnt){
  int c = threadIdx.x;                 // 128 channels
  int n0 = blockIdx.x * 64;
  if (n0 >= NN) return;
  int nend = n0 + 64; if (nend > NN) nend = NN;
  int cur = batch[n0];
  cur = (cur < 0) ? 0 : (cur >= NG ? NG - 1 : cur);
  float sum = 0.f; int count = 0;
  for (int n = n0; n < nend; n++){
    int g = batch[n];
    g = (g < 0) ? 0 : (g >= NG ? NG - 1 : g);
    if (g != cur){
      atomicAdd(&pools[cur * 128 + c], sum);
      if (c == 0) atomicAdd(&cnt[cur], count);
      sum = 0.f; count = 0; cur = g;
    }
    sum += h[(size_t)n * 128 + c];
    count++;
  }
  atomicAdd(&pools[cur * 128 + c], sum);
  if (c == 0) atomicAdd(&cnt[cur], count);
}

__global__ void final_kernel(const float* __restrict__ pools, const int* __restrict__ cnt,
                             float* __restrict__ out){
  int g = blockIdx.x, c = threadIdx.x;
  float d = fmaxf((float)cnt[g], 1.0f);
  out[g * 128 + c] = sane(pools[g * 128 + c] / d);
}

extern "C" void kernel_launch(void* const* d_in, const int* in_sizes, int n_in,
                              void* d_out, int out_size, void* d_ws, size_t ws_size,
                              hipStream_t stream){
  const void* x_raw = d_in[0];
  const int*  ei    = (const int*)d_in[1];
  const int*  bat   = (const int*)d_in[2];

  // workspace ~70 MB: control/small first, big feature buffers last
  char* w = (char*)d_ws;
  size_t o = 0;
  auto carve = [&](size_t bytes) -> char* {
    char* p = w + o; o += (bytes + 255) & ~(size_t)255; return p;
  };
  int*            flag  = (int*)carve(256);
  unsigned short* wb1   = (unsigned short*)carve((size_t)128 * 256 * 2);
  unsigned short* wb2   = (unsigned short*)carve((size_t)256 * 128 * 2);
  unsigned short* Bp1   = (unsigned short*)carve((size_t)4096 * 8 * 2);
  unsigned short* Bp2   = (unsigned short*)carve((size_t)4096 * 8 * 2);
  float*          av1   = (float*)carve(256 * 4);
  float*          dv1   = (float*)carve(256 * 4);
  float*          b1f   = (float*)carve(256 * 4);
  float*          av2   = (float*)carve(128 * 4);
  float*          dv2   = (float*)carve(128 * 4);
  float*          b2f_  = (float*)carve(128 * 4);
  float*          a_s1v = (float*)carve((size_t)NN * 4 * 4);
  float*          a_d1v = (float*)carve((size_t)NN * 4 * 4);
  float*          a_s2v = (float*)carve((size_t)NN * 4);
  float*          a_d2v = (float*)carve((size_t)NN * 4);
  int*            deg   = (int*)carve((size_t)NN * 4);
  int*            offs  = (int*)carve((size_t)(NN + 1) * 4);
  int*            cursor= (int*)carve((size_t)NN * 4);
  int*            bsums = (int*)carve(256 * 4);
  int*            csr   = (int*)carve((size_t)NET * 4);
  float*          pools = (float*)carve((size_t)NG * 128 * 4);
  int*            cnt   = (int*)carve((size_t)NG * 4);
  unsigned short* xb    = (unsigned short*)carve((size_t)NN * 128 * 2); // 12.8 MB (reused as xw2)
  unsigned short* buf   = (unsigned short*)carve((size_t)NN * 256 * 2); // 25.6 MB (xw1)
  unsigned short* h1b   = (unsigned short*)carve((size_t)NN * 256 * 2); // 25.6 MB (h1)
  unsigned short* xw2   = xb;   // xb dead after gemm1

  float* out_ge = (float*)d_out;                 // output dtype: FLOAT32 (proven r7)
  float* out_h  = (float*)d_out + NG * 128;

  hipMemsetAsync(deg,   0, (size_t)NN * 4,       stream);
  hipMemsetAsync(pools, 0, (size_t)NG * 128 * 4, stream);
  hipMemsetAsync(cnt,   0, (size_t)NG * 4,       stream);

  // ---- dtype detection + canonicalization ----
  detect_dtype<<<1, 256, 0, stream>>>((const unsigned short*)x_raw, flag);
  cvt_bf16<<<(NN * 128 + 255) / 256, 256, 0, stream>>>(x_raw, xb, NN * 128, flag);
  cvt_bf16<<<128, 256, 0, stream>>>(d_in[3], wb1, 128 * 256, flag);
  cvt_bf16<<<128, 256, 0, stream>>>(d_in[7], wb2, 256 * 128, flag);
  cvt_f32<<<1, 256, 0, stream>>>(d_in[4], av1, 256, flag);
  cvt_f32<<<1, 256, 0, stream>>>(d_in[5], dv1, 256, flag);
  cvt_f32<<<1, 256, 0, stream>>>(d_in[6], b1f, 256, flag);
  cvt_f32<<<1, 256, 0, stream>>>(d_in[8], av2, 128, flag);
  cvt_f32<<<1, 256, 0, stream>>>(d_in[9], dv2, 128, flag);
  cvt_f32<<<1, 256, 0, stream>>>(d_in[10], b2f_, 128, flag);
  pack_w<<<16, 256, 0, stream>>>(wb1, Bp1, 128, 256);
  pack_w<<<16, 256, 0, stream>>>(wb2, Bp2, 256, 128);

  // ---- CSR build (overlaps nothing it depends on) ----
  count_deg<<<(NET + 255) / 256, 256, 0, stream>>>(ei, deg);
  scan_block<<<196, 256, 0, stream>>>(deg, offs, bsums, NN);
  scan_sums<<<1, 256, 0, stream>>>(bsums, 196);
  scan_add<<<196, 256, 0, stream>>>(offs, bsums, cursor, NN);
  fill_csr<<<(NET + 255) / 256, 256, 0, stream>>>(ei, cursor, csr);

  // ---- layer 1 ----
  gemm_mfma<128, 16><<<782, 256, 0, stream>>>(xb, Bp1, buf, NN, 256);
  attn1_fast<<<12500, 256, 0, stream>>>(buf, av1, dv1, a_s1v, a_d1v);
  agg1<<<12500, 256, 0, stream>>>(buf, a_s1v, a_d1v, offs, csr, b1f, h1b);

  // ---- layer 2 ----
  gemm_mfma<256, 8><<<782, 256, 0, stream>>>(h1b, Bp2, xw2, NN, 128);
  attn2_fast<<<12500, 256, 0, stream>>>(xw2, av2, dv2, a_s2v, a_d2v);
  agg2<<<12500, 256, 0, stream>>>(xw2, a_s2v, a_d2v, offs, csr, b2f_, out_h);

  // ---- pooling ----
  pool_kernel<<<782, 128, 0, stream>>>(out_h, bat, pools, cnt);
  final_kernel<<<NG, 128, 0, stream>>>(pools, cnt, out_ge);
}

// Round 9
// 285.654 us; speedup vs baseline: 5.2658x; 1.3732x over previous
//
#include <hip/hip_runtime.h>

#define NN   50000
#define NE   400000
#define NET  450000   // NE + NN self loops
#define NG   64
#define NEG  0.2f

using bf16x8 = __attribute__((ext_vector_type(8))) short;
using f32x4  = __attribute__((ext_vector_type(4))) float;

__device__ inline float b2f(unsigned short u){
  union{unsigned int i; float f;} v; v.i = ((unsigned int)u) << 16; return v.f;
}
__device__ inline unsigned short f2b(float f){
  union{float f; unsigned int i;} v; v.f = f;
  unsigned int r = (v.i + 0x7fffu + ((v.i >> 16) & 1u)) >> 16;
  return (unsigned short)r;
}
__device__ inline float sane(float o){
  return (o > -1e30f && o < 1e30f) ? o : 0.f;
}
__device__ inline float lrelu_clamp(float e){
  e = e > 0.f ? e : NEG * e;
  return fminf(e, 60.f);          // exp-overflow guard; data is O(1), never binds
}

// ---------------- pack W (f32, K x N) -> bf16 MFMA B-fragment order ----------------
// Bp[((nt*NK + kit)*64 + lane)*8 + j] = W[(kit*32 + (lane>>4)*8 + j)*N + nt*16 + (lane&15)]
__global__ void pack_w(const float* __restrict__ W, unsigned short* __restrict__ Bp,
                       int K, int N){
  int t = blockIdx.x * blockDim.x + threadIdx.x;
  int nk = K / 32;
  int total = (N / 16) * nk * 64;
  if (t >= total) return;
  int lane = t & 63; int rest = t >> 6;
  int kit = rest % nk; int nt = rest / nk;
  int quad = lane >> 4, n = lane & 15;
  unsigned short* dst = Bp + (size_t)t * 8;
#pragma unroll
  for (int j = 0; j < 8; j++)
    dst[j] = f2b(W[(size_t)(kit*32 + quad*8 + j) * N + nt*16 + n]);
}

// ---------------- GEMM1 (f32 A 50000x128 -> bf16 C 50000x256) + fused attn coeffs ----------------
// MFMA layouts per HW-verified m91-m97: A[m=lane&15][k=quad*8+j], C col=lane&15,row=quad*4+r
__global__ void gemm1_fused(const float* __restrict__ X, const unsigned short* __restrict__ Bp,
                            const float* __restrict__ av, const float* __restrict__ dv,
                            unsigned short* __restrict__ C,
                            float* __restrict__ a_s, float* __restrict__ a_d){
  constexpr int NK = 4, NT = 16;
  int lane = threadIdx.x & 63, wave = threadIdx.x >> 6;
  int mbase = (blockIdx.x * 4 + wave) * 16;
  if (mbase >= NN) return;
  int quad = lane >> 4, nn = lane & 15;
  int arow = mbase + nn; if (arow >= NN) arow = NN - 1;
  const float* Xr = X + (size_t)arow * 128 + quad * 8;
  bf16x8 afrag[NK];
#pragma unroll
  for (int kit = 0; kit < NK; kit++){
    bf16x8 a;
#pragma unroll
    for (int j = 0; j < 8; j++) a[j] = (short)f2b(Xr[kit * 32 + j]);
    afrag[kit] = a;
  }
  float sd0=0,sd1=0,sd2=0,sd3=0, dd0=0,dd1=0,dd2=0,dd3=0;
#pragma unroll
  for (int nt = 0; nt < NT; nt++){
    f32x4 acc = {0.f, 0.f, 0.f, 0.f};
#pragma unroll
    for (int kit = 0; kit < NK; kit++){
      bf16x8 bfrag = *(const bf16x8*)(Bp + ((size_t)(nt*NK + kit) * 64 + lane) * 8);
      acc = __builtin_amdgcn_mfma_f32_16x16x32_bf16(afrag[kit], bfrag, acc, 0, 0, 0);
    }
    int col = nt * 16 + nn;
    float avc = av[col], dvc = dv[col];
    sd0 += acc[0]*avc; dd0 += acc[0]*dvc;
    sd1 += acc[1]*avc; dd1 += acc[1]*dvc;
    sd2 += acc[2]*avc; dd2 += acc[2]*dvc;
    sd3 += acc[3]*avc; dd3 += acc[3]*dvc;
#pragma unroll
    for (int r = 0; r < 4; r++){
      int row = mbase + quad * 4 + r;
      if (row < NN) C[(size_t)row * 256 + col] = f2b(acc[r]);
    }
    if ((nt & 3) == 3){                          // end of head (64 cols)
      int hh = nt >> 2;
#pragma unroll
      for (int off = 1; off < 16; off <<= 1){    // reduce over the 16 nn-lanes
        sd0 += __shfl_xor(sd0, off); sd1 += __shfl_xor(sd1, off);
        sd2 += __shfl_xor(sd2, off); sd3 += __shfl_xor(sd3, off);
        dd0 += __shfl_xor(dd0, off); dd1 += __shfl_xor(dd1, off);
        dd2 += __shfl_xor(dd2, off); dd3 += __shfl_xor(dd3, off);
      }
      if (nn == 0){
        int row = mbase + quad * 4;
        if (row + 0 < NN){ a_s[(row+0)*4+hh] = sd0; a_d[(row+0)*4+hh] = dd0; }
        if (row + 1 < NN){ a_s[(row+1)*4+hh] = sd1; a_d[(row+1)*4+hh] = dd1; }
        if (row + 2 < NN){ a_s[(row+2)*4+hh] = sd2; a_d[(row+2)*4+hh] = dd2; }
        if (row + 3 < NN){ a_s[(row+3)*4+hh] = sd3; a_d[(row+3)*4+hh] = dd3; }
      }
      sd0=sd1=sd2=sd3=dd0=dd1=dd2=dd3=0.f;
    }
  }
}

// ---------------- GEMM2 (bf16 A 50000x256 -> bf16 C 50000x128) + fused attn coeffs (1 head) ----------------
__global__ void gemm2_fused(const unsigned short* __restrict__ A, const unsigned short* __restrict__ Bp,
                            const float* __restrict__ av, const float* __restrict__ dv,
                            unsigned short* __restrict__ C,
                            float* __restrict__ a_s, float* __restrict__ a_d){
  constexpr int NK = 8, NT = 8;
  int lane = threadIdx.x & 63, wave = threadIdx.x >> 6;
  int mbase = (blockIdx.x * 4 + wave) * 16;
  if (mbase >= NN) return;
  int quad = lane >> 4, nn = lane & 15;
  int arow = mbase + nn; if (arow >= NN) arow = NN - 1;
  const unsigned short* Ar = A + (size_t)arow * 256 + quad * 8;
  bf16x8 afrag[NK];
#pragma unroll
  for (int kit = 0; kit < NK; kit++)
    afrag[kit] = *(const bf16x8*)(Ar + kit * 32);
  float sd0=0,sd1=0,sd2=0,sd3=0, dd0=0,dd1=0,dd2=0,dd3=0;
#pragma unroll
  for (int nt = 0; nt < NT; nt++){
    f32x4 acc = {0.f, 0.f, 0.f, 0.f};
#pragma unroll
    for (int kit = 0; kit < NK; kit++){
      bf16x8 bfrag = *(const bf16x8*)(Bp + ((size_t)(nt*NK + kit) * 64 + lane) * 8);
      acc = __builtin_amdgcn_mfma_f32_16x16x32_bf16(afrag[kit], bfrag, acc, 0, 0, 0);
    }
    int col = nt * 16 + nn;
    float avc = av[col], dvc = dv[col];
    sd0 += acc[0]*avc; dd0 += acc[0]*dvc;
    sd1 += acc[1]*avc; dd1 += acc[1]*dvc;
    sd2 += acc[2]*avc; dd2 += acc[2]*dvc;
    sd3 += acc[3]*avc; dd3 += acc[3]*dvc;
#pragma unroll
    for (int r = 0; r < 4; r++){
      int row = mbase + quad * 4 + r;
      if (row < NN) C[(size_t)row * 128 + col] = f2b(acc[r]);
    }
  }
#pragma unroll
  for (int off = 1; off < 16; off <<= 1){
    sd0 += __shfl_xor(sd0, off); sd1 += __shfl_xor(sd1, off);
    sd2 += __shfl_xor(sd2, off); sd3 += __shfl_xor(sd3, off);
    dd0 += __shfl_xor(dd0, off); dd1 += __shfl_xor(dd1, off);
    dd2 += __shfl_xor(dd2, off); dd3 += __shfl_xor(dd3, off);
  }
  if (nn == 0){
    int row = mbase + quad * 4;
    if (row + 0 < NN){ a_s[row+0] = sd0; a_d[row+0] = dd0; }
    if (row + 1 < NN){ a_s[row+1] = sd1; a_d[row+1] = dd1; }
    if (row + 2 < NN){ a_s[row+2] = sd2; a_d[row+2] = dd2; }
    if (row + 3 < NN){ a_s[row+3] = sd3; a_d[row+3] = dd3; }
  }
}

// ---------------- CSR build ----------------
__global__ void count_deg(const int* __restrict__ ei, int* __restrict__ deg){
  int t = blockIdx.x * blockDim.x + threadIdx.x;
  if (t >= NET) return;
  int d = (t < NE) ? ei[NE + t] : (t - NE);
  if (d < 0) d = 0; if (d >= NN) d = NN - 1;
  atomicAdd(&deg[d], 1);
}

__global__ void scan_block(const int* __restrict__ in, int* __restrict__ out_excl,
                           int* __restrict__ bsums, int n){
  __shared__ int s[256];
  int tid = threadIdx.x, gid = blockIdx.x * 256 + tid;
  int v = (gid < n) ? in[gid] : 0;
  s[tid] = v; __syncthreads();
  for (int off = 1; off < 256; off <<= 1){
    int t = (tid >= off) ? s[tid - off] : 0;
    __syncthreads();
    s[tid] += t;
    __syncthreads();
  }
  if (gid < n) out_excl[gid] = s[tid] - v;
  if (tid == 255) bsums[blockIdx.x] = s[255];
}

__global__ void scan_sums(int* __restrict__ bs, int nb){
  __shared__ int s[256];
  int tid = threadIdx.x;
  int v = (tid < nb) ? bs[tid] : 0;
  s[tid] = v; __syncthreads();
  for (int off = 1; off < 256; off <<= 1){
    int t = (tid >= off) ? s[tid - off] : 0;
    __syncthreads();
    s[tid] += t;
    __syncthreads();
  }
  if (tid < nb) bs[tid] = s[tid] - v;
}

__global__ void scan_add(int* __restrict__ offs, const int* __restrict__ bs,
                         int* __restrict__ cursor, int n){
  int gid = blockIdx.x * 256 + threadIdx.x;
  if (gid < n){
    int o = offs[gid] + bs[blockIdx.x];
    offs[gid] = o; cursor[gid] = o;
  }
  if (gid == 0) offs[n] = NET;
}

__global__ void fill_csr(const int* __restrict__ ei, int* __restrict__ cursor,
                         int* __restrict__ csr){
  int t = blockIdx.x * blockDim.x + threadIdx.x;
  if (t >= NET) return;
  int s = (t < NE) ? ei[t]      : (t - NE);
  int d = (t < NE) ? ei[NE + t] : (t - NE);
  if (d < 0) d = 0; if (d >= NN) d = NN - 1;
  int pos = atomicAdd(&cursor[d], 1);
  if (pos >= 0 && pos < NET) csr[pos] = s;
}

// ---------------- layer-1 aggregation: wave/node, no-max softmax, 4-way unrolled edges ----------------
__global__ void agg1(const unsigned short* __restrict__ xw, const float* __restrict__ a_s,
                     const float* __restrict__ a_d, const int* __restrict__ offs,
                     const int* __restrict__ csr, const float* __restrict__ bias,
                     unsigned short* __restrict__ h1){
  int lane = threadIdx.x & 63;
  int node = (blockIdx.x * blockDim.x + threadIdx.x) >> 6;
  if (node >= NN) return;
  int h = lane >> 4;
  int beg = offs[node], end = offs[node + 1];
  if (beg < 0) beg = 0; if (end > NET) end = NET;
  float adv = a_d[node * 4 + h];
  float l0=0,l1=0,l2=0,l3=0;
  float c00=0,c01=0,c02=0,c03=0;
  float c10=0,c11=0,c12=0,c13=0;
  float c20=0,c21=0,c22=0,c23=0;
  float c30=0,c31=0,c32=0,c33=0;
  int e = beg;
  for (; e + 4 <= end; e += 4){
    int s0 = csr[e], s1 = csr[e+1], s2 = csr[e+2], s3 = csr[e+3];
    float p0 = __expf(lrelu_clamp(a_s[s0*4+h] + adv));
    float p1 = __expf(lrelu_clamp(a_s[s1*4+h] + adv));
    float p2 = __expf(lrelu_clamp(a_s[s2*4+h] + adv));
    float p3 = __expf(lrelu_clamp(a_s[s3*4+h] + adv));
    ushort4 x0 = *(const ushort4*)(xw + (size_t)s0 * 256 + lane * 4);
    ushort4 x1 = *(const ushort4*)(xw + (size_t)s1 * 256 + lane * 4);
    ushort4 x2 = *(const ushort4*)(xw + (size_t)s2 * 256 + lane * 4);
    ushort4 x3 = *(const ushort4*)(xw + (size_t)s3 * 256 + lane * 4);
    l0 += p0; c00 += p0*b2f(x0.x); c01 += p0*b2f(x0.y); c02 += p0*b2f(x0.z); c03 += p0*b2f(x0.w);
    l1 += p1; c10 += p1*b2f(x1.x); c11 += p1*b2f(x1.y); c12 += p1*b2f(x1.z); c13 += p1*b2f(x1.w);
    l2 += p2; c20 += p2*b2f(x2.x); c21 += p2*b2f(x2.y); c22 += p2*b2f(x2.z); c23 += p2*b2f(x2.w);
    l3 += p3; c30 += p3*b2f(x3.x); c31 += p3*b2f(x3.y); c32 += p3*b2f(x3.z); c33 += p3*b2f(x3.w);
  }
  for (; e < end; e++){
    int s0 = csr[e];
    float p0 = __expf(lrelu_clamp(a_s[s0*4+h] + adv));
    ushort4 x0 = *(const ushort4*)(xw + (size_t)s0 * 256 + lane * 4);
    l0 += p0; c00 += p0*b2f(x0.x); c01 += p0*b2f(x0.y); c02 += p0*b2f(x0.z); c03 += p0*b2f(x0.w);
  }
  float l = l0 + l1 + l2 + l3;
  float C0 = c00 + c10 + c20 + c30;
  float C1 = c01 + c11 + c21 + c31;
  float C2 = c02 + c12 + c22 + c32;
  float C3 = c03 + c13 + c23 + c33;
  if (!(l > 0.f)) l = 1.f;
  float inv = 1.f / l;
  float4 b4 = *(const float4*)(bias + lane * 4);
  float v; ushort4 o;
  v = C0 * inv + b4.x; v = v > 0.f ? v : expm1f(v); o.x = f2b(sane(v));
  v = C1 * inv + b4.y; v = v > 0.f ? v : expm1f(v); o.y = f2b(sane(v));
  v = C2 * inv + b4.z; v = v > 0.f ? v : expm1f(v); o.z = f2b(sane(v));
  v = C3 * inv + b4.w; v = v > 0.f ? v : expm1f(v); o.w = f2b(sane(v));
  *(ushort4*)(h1 + (size_t)node * 256 + lane * 4) = o;
}

// ---------------- layer-2 aggregation: wave/node, 2 ch/lane, writes f32 h into d_out ----------------
__global__ void agg2(const unsigned short* __restrict__ xw, const float* __restrict__ a_s,
                     const float* __restrict__ a_d, const int* __restrict__ offs,
                     const int* __restrict__ csr, const float* __restrict__ bias,
                     float* __restrict__ hout){
  int lane = threadIdx.x & 63;
  int node = (blockIdx.x * blockDim.x + threadIdx.x) >> 6;
  if (node >= NN) return;
  int beg = offs[node], end = offs[node + 1];
  if (beg < 0) beg = 0; if (end > NET) end = NET;
  float adv = a_d[node];
  float l0=0,l1=0,l2=0,l3=0;
  float c00=0,c01=0, c10=0,c11=0, c20=0,c21=0, c30=0,c31=0;
  int e = beg;
  for (; e + 4 <= end; e += 4){
    int s0 = csr[e], s1 = csr[e+1], s2 = csr[e+2], s3 = csr[e+3];
    float p0 = __expf(lrelu_clamp(a_s[s0] + adv));
    float p1 = __expf(lrelu_clamp(a_s[s1] + adv));
    float p2 = __expf(lrelu_clamp(a_s[s2] + adv));
    float p3 = __expf(lrelu_clamp(a_s[s3] + adv));
    ushort2 x0 = *(const ushort2*)(xw + (size_t)s0 * 128 + lane * 2);
    ushort2 x1 = *(const ushort2*)(xw + (size_t)s1 * 128 + lane * 2);
    ushort2 x2 = *(const ushort2*)(xw + (size_t)s2 * 128 + lane * 2);
    ushort2 x3 = *(const ushort2*)(xw + (size_t)s3 * 128 + lane * 2);
    l0 += p0; c00 += p0*b2f(x0.x); c01 += p0*b2f(x0.y);
    l1 += p1; c10 += p1*b2f(x1.x); c11 += p1*b2f(x1.y);
    l2 += p2; c20 += p2*b2f(x2.x); c21 += p2*b2f(x2.y);
    l3 += p3; c30 += p3*b2f(x3.x); c31 += p3*b2f(x3.y);
  }
  for (; e < end; e++){
    int s0 = csr[e];
    float p0 = __expf(lrelu_clamp(a_s[s0] + adv));
    ushort2 x0 = *(const ushort2*)(xw + (size_t)s0 * 128 + lane * 2);
    l0 += p0; c00 += p0*b2f(x0.x); c01 += p0*b2f(x0.y);
  }
  float l = l0 + l1 + l2 + l3;
  float C0 = c00 + c10 + c20 + c30;
  float C1 = c01 + c11 + c21 + c31;
  if (!(l > 0.f)) l = 1.f;
  float inv = 1.f / l;
  float v0 = C0 * inv + bias[lane*2];   v0 = v0 > 0.f ? v0 : expm1f(v0);
  float v1 = C1 * inv + bias[lane*2+1]; v1 = v1 > 0.f ? v1 : expm1f(v1);
  float2 o; o.x = sane(v0); o.y = sane(v1);
  *(float2*)(hout + (size_t)node * 128 + lane * 2) = o;
}

// ---------------- mean pooling: sorted batch, per-block run accumulation ----------------
__global__ void pool_kernel(const float* __restrict__ h, const int* __restrict__ batch,
                            float* __restrict__ pools, int* __restrict__ cnt){
  int c = threadIdx.x;                 // 128 channels
  int n0 = blockIdx.x * 64;
  if (n0 >= NN) return;
  int nend = n0 + 64; if (nend > NN) nend = NN;
  int cur = batch[n0];
  cur = (cur < 0) ? 0 : (cur >= NG ? NG - 1 : cur);
  float sum = 0.f; int count = 0;
  for (int n = n0; n < nend; n++){
    int g = batch[n];
    g = (g < 0) ? 0 : (g >= NG ? NG - 1 : g);
    if (g != cur){
      atomicAdd(&pools[cur * 128 + c], sum);
      if (c == 0) atomicAdd(&cnt[cur], count);
      sum = 0.f; count = 0; cur = g;
    }
    sum += h[(size_t)n * 128 + c];
    count++;
  }
  atomicAdd(&pools[cur * 128 + c], sum);
  if (c == 0) atomicAdd(&cnt[cur], count);
}

__global__ void final_kernel(const float* __restrict__ pools, const int* __restrict__ cnt,
                             float* __restrict__ out){
  int g = blockIdx.x, c = threadIdx.x;
  float d = fmaxf((float)cnt[g], 1.0f);
  out[g * 128 + c] = sane(pools[g * 128 + c] / d);
}

extern "C" void kernel_launch(void* const* d_in, const int* in_sizes, int n_in,
                              void* d_out, int out_size, void* d_ws, size_t ws_size,
                              hipStream_t stream){
  const float* x    = (const float*)d_in[0];     // f32, HW-proven r5/r7
  const int*   ei   = (const int*)d_in[1];
  const int*   bat  = (const int*)d_in[2];
  const float* W1   = (const float*)d_in[3];
  const float* av1  = (const float*)d_in[4];
  const float* dv1  = (const float*)d_in[5];
  const float* b1   = (const float*)d_in[6];
  const float* W2   = (const float*)d_in[7];
  const float* av2  = (const float*)d_in[8];
  const float* dv2  = (const float*)d_in[9];
  const float* b2   = (const float*)d_in[10];

  char* w = (char*)d_ws;
  size_t o = 0;
  auto carve = [&](size_t bytes) -> char* {
    char* p = w + o; o += (bytes + 255) & ~(size_t)255; return p;
  };
  unsigned short* Bp1   = (unsigned short*)carve((size_t)4096 * 8 * 2);
  unsigned short* Bp2   = (unsigned short*)carve((size_t)4096 * 8 * 2);
  float*          a_s1v = (float*)carve((size_t)NN * 4 * 4);
  float*          a_d1v = (float*)carve((size_t)NN * 4 * 4);
  float*          a_s2v = (float*)carve((size_t)NN * 4);
  float*          a_d2v = (float*)carve((size_t)NN * 4);
  int*            deg   = (int*)carve((size_t)NN * 4);
  int*            offs  = (int*)carve((size_t)(NN + 1) * 4);
  int*            cursor= (int*)carve((size_t)NN * 4);
  int*            bsums = (int*)carve(256 * 4);
  int*            csr   = (int*)carve((size_t)NET * 4);
  float*          pools = (float*)carve((size_t)NG * 128 * 4);
  int*            cnt   = (int*)carve((size_t)NG * 4);
  unsigned short* xw1   = (unsigned short*)carve((size_t)NN * 256 * 2);  // 25.6 MB
  unsigned short* h1b   = (unsigned short*)carve((size_t)NN * 256 * 2);  // 25.6 MB
  unsigned short* xw2   = (unsigned short*)carve((size_t)NN * 128 * 2);  // 12.8 MB

  float* out_ge = (float*)d_out;                 // output dtype f32 (proven r7)
  float* out_h  = (float*)d_out + NG * 128;

  hipMemsetAsync(deg,   0, (size_t)NN * 4,       stream);
  hipMemsetAsync(pools, 0, (size_t)NG * 128 * 4, stream);
  hipMemsetAsync(cnt,   0, (size_t)NG * 4,       stream);

  pack_w<<<16, 256, 0, stream>>>(W1, Bp1, 128, 256);
  pack_w<<<16, 256, 0, stream>>>(W2, Bp2, 256, 128);

  count_deg<<<(NET + 255) / 256, 256, 0, stream>>>(ei, deg);
  scan_block<<<196, 256, 0, stream>>>(deg, offs, bsums, NN);
  scan_sums<<<1, 256, 0, stream>>>(bsums, 196);
  scan_add<<<196, 256, 0, stream>>>(offs, bsums, cursor, NN);
  fill_csr<<<(NET + 255) / 256, 256, 0, stream>>>(ei, cursor, csr);

  gemm1_fused<<<782, 256, 0, stream>>>(x, Bp1, av1, dv1, xw1, a_s1v, a_d1v);
  agg1<<<12500, 256, 0, stream>>>(xw1, a_s1v, a_d1v, offs, csr, b1, h1b);

  gemm2_fused<<<782, 256, 0, stream>>>(h1b, Bp2, av2, dv2, xw2, a_s2v, a_d2v);
  agg2<<<12500, 256, 0, stream>>>(xw2, a_s2v, a_d2v, offs, csr, b2, out_h);

  pool_kernel<<<782, 128, 0, stream>>>(out_h, bat, pools, cnt);
  final_kernel<<<NG, 128, 0, stream>>>(pools, cnt, out_ge);
}